// Round 1
// baseline (2319.102 us; speedup 1.0000x reference)
//
#include <hip/hip_runtime.h>
#include <hip/hip_bf16.h>

// Problem constants
#define BB  8
#define MM  1024
#define DD  1024
#define HH  16
#define FF  4096
#define NL  4
#define DKK 64

typedef __bf16 bf16_t;
typedef __bf16 bf16x8 __attribute__((ext_vector_type(8)));
typedef __bf16 bf16x4 __attribute__((ext_vector_type(4)));
typedef float  f32x4  __attribute__((ext_vector_type(4)));

// async global->LDS, 16B per lane. LDS dest = wave-uniform base + lane*16.
__device__ __forceinline__ void gld16(const bf16_t* g, bf16_t* l) {
    __builtin_amdgcn_global_load_lds((const __attribute__((address_space(1))) void*)g,
                                     (__attribute__((address_space(3))) void*)l,
                                     16, 0, 0);
}

// ---------------------------------------------------------------------------
// x init: copy embeds -> x (fp32) and xb (bf16)
// ---------------------------------------------------------------------------
__global__ __launch_bounds__(256) void cvt_x(const float* __restrict__ e,
                                             float* __restrict__ x,
                                             bf16_t* __restrict__ xb) {
    size_t i = ((size_t)blockIdx.x * 256 + threadIdx.x) * 4;
    float4 v = *(const float4*)(e + i);
    *(float4*)(x + i) = v;
    bf16x4 o;
    o[0] = (bf16_t)v.x; o[1] = (bf16_t)v.y; o[2] = (bf16_t)v.z; o[3] = (bf16_t)v.w;
    *(bf16x4*)(xb + i) = o;
}

// ---------------------------------------------------------------------------
// One launch per layer: transpose+cvt all six weight matrices.
// ---------------------------------------------------------------------------
__global__ __launch_bounds__(256) void transpose_all(const float* __restrict__ Wq,
                                                     const float* __restrict__ Wk,
                                                     const float* __restrict__ Wv,
                                                     const float* __restrict__ Wo,
                                                     const float* __restrict__ W1,
                                                     const float* __restrict__ W2,
                                                     bf16_t* __restrict__ qkvT,
                                                     bf16_t* __restrict__ WoT,
                                                     bf16_t* __restrict__ W1T,
                                                     bf16_t* __restrict__ W2T) {
    __shared__ float tile[32][33];
    const int bx = blockIdx.x;
    const float* in;
    bf16_t* out;
    int C, t;
    if (bx < 4096) {
        const int mat = bx >> 10;
        t = bx & 1023;
        C = 1024;
        in  = mat == 0 ? Wq : mat == 1 ? Wk : mat == 2 ? Wv : Wo;
        out = mat < 3 ? qkvT + (size_t)mat * DD * DD : WoT;
    } else if (bx < 8192) {
        t = bx - 4096; C = 4096; in = W1; out = W1T;
    } else {
        t = bx - 8192; C = 1024; in = W2; out = W2T;
    }
    const int cb = C >> 5;
    const int c0 = (t % cb) * 32, r0 = (t / cb) * 32;
    const int R = (C == 1024) ? ((bx < 8192) ? 1024 : 4096) : 1024;
    const int tx = threadIdx.x & 31, ty = threadIdx.x >> 5;  // 32 x 8
    for (int i = 0; i < 4; i++)
        tile[ty + i * 8][tx] = in[(size_t)(r0 + ty + i * 8) * C + c0 + tx];
    __syncthreads();
    for (int i = 0; i < 4; i++)
        out[(size_t)(c0 + ty + i * 8) * R + r0 + tx] = (bf16_t)tile[tx][ty + i * 8];
}

// ---------------------------------------------------------------------------
// concat bq|bk|bv for all 4 layers -> qkvB[l][3072]
// ---------------------------------------------------------------------------
__global__ __launch_bounds__(256) void concat_bias(const float* __restrict__ bq,
                                                   const float* __restrict__ bk,
                                                   const float* __restrict__ bv,
                                                   float* __restrict__ out) {
    const int seg = blockIdx.x, l = blockIdx.y, t = threadIdx.x;
    const float* src = seg == 0 ? bq : seg == 1 ? bk : bv;
    float4 v = *(const float4*)(src + (size_t)l * 1024 + t * 4);
    *(float4*)(out + (size_t)l * 3072 + seg * 1024 + t * 4) = v;
}

// ---------------------------------------------------------------------------
// v slice of fused qkv (stride ld) -> vT (B,H,DK,M) bf16
// ---------------------------------------------------------------------------
__global__ __launch_bounds__(256) void transpose_v_k(const bf16_t* __restrict__ v,
                                                     bf16_t* __restrict__ vT, int ld) {
    __shared__ bf16_t t[64][65];
    int bh = blockIdx.y, b = bh >> 4, h = bh & 15;
    int m0 = blockIdx.x * 64;
    int tx = threadIdx.x & 63, ty = threadIdx.x >> 6;  // ty 0..3
    for (int i = 0; i < 16; i++) {
        int mr = ty * 16 + i;
        t[mr][tx] = v[(size_t)(b * MM + m0 + mr) * ld + h * DKK + tx];
    }
    __syncthreads();
    for (int i = 0; i < 16; i++) {
        int dk = ty * 16 + i;
        vT[((size_t)(bh * DKK + dk)) * MM + m0 + tx] = t[tx][dk];
    }
}

// ---------------------------------------------------------------------------
// 256x256-tile deep-pipelined GEMM (T2+T3+T4+T5 stack):
//   C(8192 x Ntot) = A(bf16, 8192 x K) @ Bt(bf16, Ntot x K)^T + bias
// 8 waves (2M x 4N), per-wave 128x64, BK=64 split into two K=32 planes.
// LDS [buf][kplane][256][32] double-buffered (128 KiB): each plane is a
// contiguous 16 KiB region staged by 4 gld16/thread-phase; regions ping-pong
// into slots whose reads completed exactly one phase earlier.
// Per phase: 12 ds_read_b128 -> barrier -> 32 MFMA (setprio) ->
//            s_waitcnt vmcnt(8) + s_barrier   (8 loads in flight ALWAYS;
//            stage-to-consume distance = 3 phases; never drains to 0).
// XOR swizzle: LDS[row][blk16B] holds global blk (blk ^ ((row>>1)&3)) --
// uniform 8 lanes per 16B bank-slot on ds_read_b128 (conflict-free, m136),
// applied on the GLOBAL side so the gld16 LDS dest stays linear (m173).
// EPI: 0 = bf16 store; 1 = fp32 store of (C + bias + res); 2 = exact-GELU bf16
// Requires: M % 256 == 0, Ntot % 256 == 0, K % 128 == 0.
// ---------------------------------------------------------------------------
__device__ __forceinline__ void stage_plane(const bf16_t* __restrict__ G, int K,
                                            size_t rbase, size_t kcol0,
                                            bf16_t* lds, int w, int srow, int scol) {
#pragma unroll
    for (int j = 0; j < 2; j++)
        gld16(G + (rbase + (size_t)(j * 128 + w * 16 + srow)) * (size_t)K + kcol0 + scol,
              lds + j * 4096 + w * 512);
}

template <int EPI>
__global__ __launch_bounds__(512, 2) void gemm256(const bf16_t* __restrict__ A,
                                                  const bf16_t* __restrict__ Bt,
                                                  const float* __restrict__ bias,
                                                  const float* __restrict__ res,
                                                  bf16_t* __restrict__ outb,
                                                  float* __restrict__ outf,
                                                  int K, int Ntot) {
    __shared__ __align__(16) bf16_t As[2 * 2 * 256 * 32];   // [buf][kplane][256][32]
    __shared__ __align__(16) bf16_t Bs[2 * 2 * 256 * 32];
    const int tid = threadIdx.x, w = tid >> 6, lane = tid & 63;
    const int fr = lane & 15, quad = lane >> 4;
    const int wm = w >> 2, wn = w & 3;
    const int srow = lane >> 2;                               // staging row-in-16
    const int scol = ((lane & 3) ^ ((lane >> 3) & 3)) << 3;   // pre-swizzled global col
    const int swz  = (quad ^ ((fr >> 1) & 3)) << 3;           // read-side swizzle

    // bijective XCD-aware block swizzle (m204)
    const int gx = gridDim.x;
    int lid = blockIdx.y * gx + blockIdx.x;
    {
        const int nwg = gx * gridDim.y;
        const int qq = nwg >> 3, rr = nwg & 7, xc = lid & 7, lq = lid >> 3;
        lid = (xc < rr ? xc * (qq + 1) : rr * (qq + 1) + (xc - rr) * qq) + lq;
    }
    const size_t bm = (size_t)(lid / gx) * 256;
    const size_t bn = (size_t)(lid % gx) * 256;

    const int NT = K >> 6;    // K-tiles of 64 (even: K is 1024 or 4096)
    f32x4 acc[8][4] = {};

    // prologue: t0.plane0 -> buf0, t0.plane1 -> buf0, t1.plane0 -> buf1
    stage_plane(A,  K, bm, 0,  As,         w, srow, scol);
    stage_plane(Bt, K, bn, 0,  Bs,         w, srow, scol);
    stage_plane(A,  K, bm, 32, As + 8192,  w, srow, scol);
    stage_plane(Bt, K, bn, 32, Bs + 8192,  w, srow, scol);
    stage_plane(A,  K, bm, 64, As + 16384, w, srow, scol);
    stage_plane(Bt, K, bn, 64, Bs + 16384, w, srow, scol);
    asm volatile("s_waitcnt vmcnt(8)\n\ts_barrier" ::: "memory");

    auto phase = [&](int rdbase, int stbase, size_t stk) {
        bf16x8 af[8], bfv[4];
        const bf16_t* Ap = As + rdbase;
        const bf16_t* Bp = Bs + rdbase;
#pragma unroll
        for (int i = 0; i < 8; i++)
            af[i] = *(const bf16x8*)&Ap[(wm * 128 + i * 16 + fr) * 32 + swz];
#pragma unroll
        for (int j = 0; j < 4; j++)
            bfv[j] = *(const bf16x8*)&Bp[(wn * 64 + j * 16 + fr) * 32 + swz];
        stage_plane(A,  K, bm, stk, As + stbase, w, srow, scol);
        stage_plane(Bt, K, bn, stk, Bs + stbase, w, srow, scol);
        asm volatile("s_barrier" ::: "memory");
        __builtin_amdgcn_s_setprio(1);
#pragma unroll
        for (int i = 0; i < 8; i++)
#pragma unroll
            for (int j = 0; j < 4; j++)
                acc[i][j] = __builtin_amdgcn_mfma_f32_16x16x32_bf16(af[i], bfv[j],
                                                                    acc[i][j], 0, 0, 0);
        __builtin_amdgcn_s_setprio(0);
        asm volatile("s_waitcnt vmcnt(8)\n\ts_barrier" ::: "memory");
    };

    for (int t = 0; t < NT; t += 2) {
        const size_t t1 = (t + 1 < NT) ? t + 1 : NT - 1;   // clamped tail stages keep
        const size_t t2 = (t + 2 < NT) ? t + 2 : NT - 1;   // the vmcnt count uniform
        const size_t t3 = (t + 3 < NT) ? t + 3 : NT - 1;
        // tile t   (buf0): read buf0.p0, stage buf1.p1 <- t1.p1
        phase(0,     24576, t1 * 64 + 32);
        //                  read buf0.p1, stage buf0.p0 <- t2.p0
        phase(8192,  0,     t2 * 64);
        // tile t+1 (buf1): read buf1.p0, stage buf0.p1 <- t2.p1
        phase(16384, 8192,  t2 * 64 + 32);
        //                  read buf1.p1, stage buf1.p0 <- t3.p0
        phase(24576, 16384, t3 * 64);
    }

    // epilogue: C layout col = lane&15, row = quad*4 + reg
#pragma unroll
    for (int j = 0; j < 4; j++) {
        const size_t c = bn + wn * 64 + j * 16 + fr;
        const float bv = bias[c];
#pragma unroll
        for (int i = 0; i < 8; i++) {
            const size_t rbase = bm + wm * 128 + i * 16 + quad * 4;
#pragma unroll
            for (int r = 0; r < 4; r++) {
                const size_t idx = (rbase + r) * (size_t)Ntot + c;
                float v = acc[i][j][r] + bv;
                if constexpr (EPI == 0) {
                    outb[idx] = (bf16_t)v;
                } else if constexpr (EPI == 1) {
                    outf[idx] = v + res[idx];
                } else {
                    float g = 0.5f * v * (1.0f + erff(v * 0.70710678118654752f));
                    outb[idx] = (bf16_t)g;
                }
            }
        }
    }
}

// ---------------------------------------------------------------------------
// Flash attention: one block per (b, h, 64 Q rows). K-tiles of 128.
// No max-rescaling (scores sigma ~3, overflow needs ~26 sigma). Ps aliases Ks.
// ---------------------------------------------------------------------------
__global__ __launch_bounds__(256) void flash_attn(const bf16_t* __restrict__ q,
                                                  const bf16_t* __restrict__ kmat,
                                                  const bf16_t* __restrict__ vT,
                                                  const float* __restrict__ wts,
                                                  bf16_t* __restrict__ ao, int ldq) {
    __shared__ bf16_t Ks[128 * 72];   // [key][dk] pad 64->72; aliased by Ps[64][136]
    __shared__ bf16_t Vs[64 * 136];   // [dk][key] pad 128->136
    bf16_t* Ps = Ks;

    const int tid = threadIdx.x;
    const int wave = tid >> 6, lane = tid & 63;
    const int fr = lane & 15, quad = lane >> 4;
    const int fk = quad * 8;
    const int bh = blockIdx.y, b = bh >> 4, h = bh & 15;
    const int q0 = blockIdx.x * 64;

    const size_t qrow = (size_t)(b * MM + q0 + wave * 16 + fr) * ldq + h * DKK;
    const bf16x8 aq0 = *(const bf16x8*)(q + qrow + fk);
    const bf16x8 aq1 = *(const bf16x8*)(q + qrow + 32 + fk);

    f32x4 oacc[4] = {};
    float lrow[4] = {0.f, 0.f, 0.f, 0.f};

    for (int kt = 0; kt < MM; kt += 128) {
        __syncthreads();
#pragma unroll
        for (int rr = 0; rr < 4; rr++) {
            const int key = rr * 32 + (tid >> 3);
            const int dkc = (tid & 7) * 8;
            *(bf16x8*)(&Ks[key * 72 + dkc]) =
                *(const bf16x8*)(kmat + (size_t)(b * MM + kt + key) * ldq + h * DKK + dkc);
            const int dkr = rr * 16 + (tid >> 4);
            const int kc = (tid & 15) * 8;
            *(bf16x8*)(&Vs[dkr * 136 + kc]) =
                *(const bf16x8*)(vT + (size_t)(bh * DKK + dkr) * MM + kt + kc);
        }
        __syncthreads();

        f32x4 s[8];
#pragma unroll
        for (int ni = 0; ni < 8; ni++) {
            const bf16_t* kp = &Ks[(ni * 16 + fr) * 72];
            f32x4 z = {0.f, 0.f, 0.f, 0.f};
            z = __builtin_amdgcn_mfma_f32_16x16x32_bf16(aq0, *(const bf16x8*)(kp + fk), z, 0, 0, 0);
            z = __builtin_amdgcn_mfma_f32_16x16x32_bf16(aq1, *(const bf16x8*)(kp + 32 + fk), z, 0, 0, 0);
            const float wv = wts[b * MM + kt + ni * 16 + fr];
#pragma unroll
            for (int r = 0; r < 4; r++) s[ni][r] = __expf(z[r] * 0.125f + wv);
        }

        float rs[4] = {0.f, 0.f, 0.f, 0.f};
#pragma unroll
        for (int ni = 0; ni < 8; ni++)
#pragma unroll
            for (int r = 0; r < 4; r++) rs[r] += s[ni][r];
#pragma unroll
        for (int off = 1; off < 16; off <<= 1)
#pragma unroll
            for (int r = 0; r < 4; r++) rs[r] += __shfl_xor(rs[r], off, 16);
#pragma unroll
        for (int r = 0; r < 4; r++) lrow[r] += rs[r];

        __syncthreads();   // all waves done reading Ks before P overwrites it

#pragma unroll
        for (int ni = 0; ni < 8; ni++)
#pragma unroll
            for (int r = 0; r < 4; r++)
                Ps[(wave * 16 + quad * 4 + r) * 136 + ni * 16 + fr] = (bf16_t)s[ni][r];

#pragma unroll
        for (int c2 = 0; c2 < 4; c2++) {
            const bf16x8 ap = *(const bf16x8*)(&Ps[(wave * 16 + fr) * 136 + c2 * 32 + fk]);
#pragma unroll
            for (int ni = 0; ni < 4; ni++) {
                const bf16x8 bv = *(const bf16x8*)(&Vs[(ni * 16 + fr) * 136 + c2 * 32 + fk]);
                oacc[ni] = __builtin_amdgcn_mfma_f32_16x16x32_bf16(ap, bv, oacc[ni], 0, 0, 0);
            }
        }
    }

    const size_t orow = (size_t)(b * MM + q0 + wave * 16 + quad * 4);
#pragma unroll
    for (int ni = 0; ni < 4; ni++)
#pragma unroll
        for (int r = 0; r < 4; r++) {
            const float ov = oacc[ni][r] / lrow[r];
            ao[(orow + r) * DD + h * DKK + ni * 16 + fr] = (bf16_t)ov;
        }
}

// ---------------------------------------------------------------------------
// LayerNorm over rows of D=1024: out fp32 + bf16 copy
// ---------------------------------------------------------------------------
__global__ __launch_bounds__(256) void ln_k(const float* __restrict__ in,
                                            const float* __restrict__ g,
                                            const float* __restrict__ be,
                                            float* __restrict__ xout,
                                            bf16_t* __restrict__ xb) {
    const int row = blockIdx.x, t = threadIdx.x;
    const float* rp = in + (size_t)row * DD;
    float4 v = *(const float4*)(rp + t * 4);
    float s = v.x + v.y + v.z + v.w;
    float ss = v.x * v.x + v.y * v.y + v.z * v.z + v.w * v.w;
    for (int off = 1; off < 64; off <<= 1) {
        s += __shfl_xor(s, off);
        ss += __shfl_xor(ss, off);
    }
    __shared__ float sb[4], ssb[4];
    if ((t & 63) == 0) { sb[t >> 6] = s; ssb[t >> 6] = ss; }
    __syncthreads();
    s = sb[0] + sb[1] + sb[2] + sb[3];
    ss = ssb[0] + ssb[1] + ssb[2] + ssb[3];
    const float mu = s * (1.0f / DD);
    const float var = ss * (1.0f / DD) - mu * mu;
    const float rstd = rsqrtf(var + 1e-5f);
    float4 gg = *(const float4*)(g + t * 4);
    float4 bb = *(const float4*)(be + t * 4);
    float o0 = (v.x - mu) * rstd * gg.x + bb.x;
    float o1 = (v.y - mu) * rstd * gg.y + bb.y;
    float o2 = (v.z - mu) * rstd * gg.z + bb.z;
    float o3 = (v.w - mu) * rstd * gg.w + bb.w;
    *(float4*)(xout + (size_t)row * DD + t * 4) = make_float4(o0, o1, o2, o3);
    bf16x4 ob;
    ob[0] = (bf16_t)o0; ob[1] = (bf16_t)o1; ob[2] = (bf16_t)o2; ob[3] = (bf16_t)o3;
    *(bf16x4*)(xb + (size_t)row * DD + t * 4) = ob;
}

// ---------------------------------------------------------------------------
extern "C" void kernel_launch(void* const* d_in, const int* in_sizes, int n_in,
                              void* d_out, int out_size, void* d_ws, size_t ws_size,
                              hipStream_t stream) {
    const float* embeds = (const float*)d_in[0];
    const float* wts    = (const float*)d_in[1];
    const float* Wq = (const float*)d_in[2];
    const float* bq = (const float*)d_in[3];
    const float* Wk = (const float*)d_in[4];
    const float* bk = (const float*)d_in[5];
    const float* Wv = (const float*)d_in[6];
    const float* bv = (const float*)d_in[7];
    const float* Wo = (const float*)d_in[8];
    const float* bo = (const float*)d_in[9];
    const float* W1 = (const float*)d_in[10];
    const float* b1 = (const float*)d_in[11];
    const float* W2 = (const float*)d_in[12];
    const float* b2 = (const float*)d_in[13];
    const float* g1 = (const float*)d_in[14];
    const float* be1 = (const float*)d_in[15];
    const float* g2 = (const float*)d_in[16];
    const float* be2 = (const float*)d_in[17];
    float* x = (float*)d_out;

    char* p = (char*)d_ws;
    auto take = [&](size_t n) { char* r = p; p += (n + 255) & ~(size_t)255; return r; };
    const size_t nBMD = (size_t)BB * MM * DD;
    bf16_t* xb   = (bf16_t*)take(nBMD * 2);
    bf16_t* qkvb = (bf16_t*)take(nBMD * 3 * 2);
    bf16_t* vTb  = (bf16_t*)take(nBMD * 2);
    float*  r1   = (float*)take(nBMD * 4);
    float*  x1   = (float*)take(nBMD * 4);
    bf16_t* hb   = (bf16_t*)take((size_t)BB * MM * FF * 2);
    bf16_t* qkvT = (bf16_t*)take((size_t)3 * DD * DD * 2);
    bf16_t* WoT  = (bf16_t*)take((size_t)DD * DD * 2);
    bf16_t* W1T  = (bf16_t*)take((size_t)DD * FF * 2);
    bf16_t* W2T  = (bf16_t*)take((size_t)DD * FF * 2);
    float*  qkvB = (float*)take((size_t)NL * 3072 * 4);
    bf16_t* aob  = hb;   // hb is free until FFN1
    bf16_t* x1b  = xb;   // xb is dead after the QKV GEMM

    cvt_x<<<8192, 256, 0, stream>>>(embeds, x, xb);
    concat_bias<<<dim3(3, NL), 256, 0, stream>>>(bq, bk, bv, qkvB);

    const dim3 gQKV(3072 / 256, (BB * MM) / 256);   // (12, 32)
    const dim3 gDD(DD / 256, (BB * MM) / 256);      // (4, 32)
    const dim3 gF1(FF / 256, (BB * MM) / 256);      // (16, 32)

    for (int l = 0; l < NL; l++) {
        transpose_all<<<12288, 256, 0, stream>>>(
            Wq + (size_t)l * DD * DD, Wk + (size_t)l * DD * DD,
            Wv + (size_t)l * DD * DD, Wo + (size_t)l * DD * DD,
            W1 + (size_t)l * DD * FF, W2 + (size_t)l * FF * DD,
            qkvT, WoT, W1T, W2T);

        gemm256<0><<<gQKV, 512, 0, stream>>>(xb, qkvT, qkvB + (size_t)l * 3072,
                                             nullptr, qkvb, nullptr, DD, 3072);

        transpose_v_k<<<dim3(16, 128), 256, 0, stream>>>(qkvb + 2048, vTb, 3072);
        flash_attn<<<dim3(16, 128), 256, 0, stream>>>(qkvb, qkvb + 1024, vTb, wts, aob, 3072);

        gemm256<1><<<gDD, 512, 0, stream>>>(aob, WoT, bo + (size_t)l * DD, x, nullptr, r1, DD, DD);
        ln_k<<<BB * MM, 256, 0, stream>>>(r1, g1 + (size_t)l * DD, be1 + (size_t)l * DD, x1, x1b);

        gemm256<2><<<gF1, 512, 0, stream>>>(x1b, W1T, b1 + (size_t)l * FF, nullptr, hb, nullptr, DD, FF);
        gemm256<1><<<gDD, 512, 0, stream>>>(hb, W2T, b2 + (size_t)l * DD, x1, nullptr, r1, FF, DD);
        ln_k<<<BB * MM, 256, 0, stream>>>(r1, g2 + (size_t)l * DD, be2 + (size_t)l * DD, x, xb);
    }
}

// Round 2
// 2081.970 us; speedup vs baseline: 1.1139x; 1.1139x over previous
//
#include <hip/hip_runtime.h>
#include <hip/hip_bf16.h>

// Problem constants
#define BB  8
#define MM  1024
#define DD  1024
#define HH  16
#define FF  4096
#define NL  4
#define DKK 64

typedef __bf16 bf16_t;
typedef __bf16 bf16x8 __attribute__((ext_vector_type(8)));
typedef __bf16 bf16x4 __attribute__((ext_vector_type(4)));
typedef float  f32x4  __attribute__((ext_vector_type(4)));

// async global->LDS, 16B per lane. LDS dest = wave-uniform base + lane*16.
__device__ __forceinline__ void gld16(const bf16_t* g, bf16_t* l) {
    __builtin_amdgcn_global_load_lds((const __attribute__((address_space(1))) void*)g,
                                     (__attribute__((address_space(3))) void*)l,
                                     16, 0, 0);
}

// ---------------------------------------------------------------------------
// x init: copy embeds -> x (fp32) and xb (bf16)
// ---------------------------------------------------------------------------
__global__ __launch_bounds__(256) void cvt_x(const float* __restrict__ e,
                                             float* __restrict__ x,
                                             bf16_t* __restrict__ xb) {
    size_t i = ((size_t)blockIdx.x * 256 + threadIdx.x) * 4;
    float4 v = *(const float4*)(e + i);
    *(float4*)(x + i) = v;
    bf16x4 o;
    o[0] = (bf16_t)v.x; o[1] = (bf16_t)v.y; o[2] = (bf16_t)v.z; o[3] = (bf16_t)v.w;
    *(bf16x4*)(xb + i) = o;
}

// ---------------------------------------------------------------------------
// One launch per layer: transpose+cvt all six weight matrices.
// ---------------------------------------------------------------------------
__global__ __launch_bounds__(256) void transpose_all(const float* __restrict__ Wq,
                                                     const float* __restrict__ Wk,
                                                     const float* __restrict__ Wv,
                                                     const float* __restrict__ Wo,
                                                     const float* __restrict__ W1,
                                                     const float* __restrict__ W2,
                                                     bf16_t* __restrict__ qkvT,
                                                     bf16_t* __restrict__ WoT,
                                                     bf16_t* __restrict__ W1T,
                                                     bf16_t* __restrict__ W2T) {
    __shared__ float tile[32][33];
    const int bx = blockIdx.x;
    const float* in;
    bf16_t* out;
    int C, t;
    if (bx < 4096) {
        const int mat = bx >> 10;
        t = bx & 1023;
        C = 1024;
        in  = mat == 0 ? Wq : mat == 1 ? Wk : mat == 2 ? Wv : Wo;
        out = mat < 3 ? qkvT + (size_t)mat * DD * DD : WoT;
    } else if (bx < 8192) {
        t = bx - 4096; C = 4096; in = W1; out = W1T;
    } else {
        t = bx - 8192; C = 1024; in = W2; out = W2T;
    }
    const int cb = C >> 5;
    const int c0 = (t % cb) * 32, r0 = (t / cb) * 32;
    const int R = (C == 1024) ? ((bx < 8192) ? 1024 : 4096) : 1024;
    const int tx = threadIdx.x & 31, ty = threadIdx.x >> 5;  // 32 x 8
    for (int i = 0; i < 4; i++)
        tile[ty + i * 8][tx] = in[(size_t)(r0 + ty + i * 8) * C + c0 + tx];
    __syncthreads();
    for (int i = 0; i < 4; i++)
        out[(size_t)(c0 + ty + i * 8) * R + r0 + tx] = (bf16_t)tile[tx][ty + i * 8];
}

// ---------------------------------------------------------------------------
// concat bq|bk|bv for all 4 layers -> qkvB[l][3072]
// ---------------------------------------------------------------------------
__global__ __launch_bounds__(256) void concat_bias(const float* __restrict__ bq,
                                                   const float* __restrict__ bk,
                                                   const float* __restrict__ bv,
                                                   float* __restrict__ out) {
    const int seg = blockIdx.x, l = blockIdx.y, t = threadIdx.x;
    const float* src = seg == 0 ? bq : seg == 1 ? bk : bv;
    float4 v = *(const float4*)(src + (size_t)l * 1024 + t * 4);
    *(float4*)(out + (size_t)l * 3072 + seg * 1024 + t * 4) = v;
}

// ---------------------------------------------------------------------------
// v slice of fused qkv (stride ld) -> vT (B,H,DK,M) bf16
// ---------------------------------------------------------------------------
__global__ __launch_bounds__(256) void transpose_v_k(const bf16_t* __restrict__ v,
                                                     bf16_t* __restrict__ vT, int ld) {
    __shared__ bf16_t t[64][65];
    int bh = blockIdx.y, b = bh >> 4, h = bh & 15;
    int m0 = blockIdx.x * 64;
    int tx = threadIdx.x & 63, ty = threadIdx.x >> 6;  // ty 0..3
    for (int i = 0; i < 16; i++) {
        int mr = ty * 16 + i;
        t[mr][tx] = v[(size_t)(b * MM + m0 + mr) * ld + h * DKK + tx];
    }
    __syncthreads();
    for (int i = 0; i < 16; i++) {
        int dk = ty * 16 + i;
        vT[((size_t)(bh * DKK + dk)) * MM + m0 + tx] = t[tx][dk];
    }
}

// ---------------------------------------------------------------------------
// 256x128-tile deep-pipelined GEMM (T2+T3+T4+T5 stack, m201-idiom barriers):
//   C(8192 x Ntot) = A(bf16, 8192 x K) @ Bt(bf16, Ntot x K)^T + bias
// 8 waves (4M x 2N), per-wave 64x64 output, BK=64 as two K=32 planes.
// LDS: 4 plane-slots per matrix (A: 4x[256][32]=64KB, B: 4x[128][32]=32KB).
// Phase = { 8 ds_read_b128 (frags for this plane) ; 3 gld16 (stage one
//           A-plane + one B-plane, 3 phases ahead) ; s_barrier ;
//           setprio(1) 16 MFMA setprio(0) ; s_waitcnt vmcnt(6) ; s_barrier }
// 3 loads/phase, vmcnt(6) -> stage-to-consume distance exactly 3 phases for
// every slot; count NEVER drains to 0 in the loop (T4). One vmcnt(0) after
// the loop so no gld16 is in flight at LDS dealloc.
// XOR swizzle: LDS[row][blk16B] = global[row][blk ^ ((row>>1)&3)], applied on
// the GLOBAL source (gld16 dest must stay linear, m173); fragment reads use
// blk = quad ^ ((fr>>1)&3)  -> 0 bank conflicts (verified r1).
// Grids: all outputs give exact multiples of 256 blocks (full machine).
// EPI: 0 = bf16 store; 1 = fp32 store of (C + bias + res); 2 = exact-GELU bf16
// Requires: M % 256 == 0, Ntot % 128 == 0, K % 128 == 0.
// ---------------------------------------------------------------------------
template <int EPI>
__global__ __launch_bounds__(512, 2) void gemm_k(const bf16_t* __restrict__ A,
                                                 const bf16_t* __restrict__ Bt,
                                                 const float* __restrict__ bias,
                                                 const float* __restrict__ res,
                                                 bf16_t* __restrict__ outb,
                                                 float* __restrict__ outf,
                                                 int K, int Ntot) {
    __shared__ __align__(16) bf16_t As[4 * 256 * 32];   // 4 slots x 16KB
    __shared__ __align__(16) bf16_t Bs[4 * 128 * 32];   // 4 slots x 8KB
    const int tid = threadIdx.x, w = tid >> 6, lane = tid & 63;
    const int fr = lane & 15, quad = lane >> 4;
    const int wm = w >> 1, wn = w & 1;
    const int srow = lane >> 2;                               // staging row-in-16
    const int scol = ((lane & 3) ^ ((lane >> 3) & 3)) << 3;   // pre-swizzled global col
    const int swz  = (quad ^ ((fr >> 1) & 3)) << 3;           // read-side swizzle

    // bijective XCD-aware block swizzle (m204)
    const int gx = gridDim.x;
    int lid = blockIdx.y * gx + blockIdx.x;
    {
        const int nwg = gx * gridDim.y;
        const int qq = nwg >> 3, rr = nwg & 7, xc = lid & 7, lq = lid >> 3;
        lid = (xc < rr ? xc * (qq + 1) : rr * (qq + 1) + (xc - rr) * qq) + lq;
    }
    const size_t bm = (size_t)(lid / gx) * 256;
    const size_t bn = (size_t)(lid % gx) * 128;

    const int NT = K >> 6;    // K-tiles of 64 (K is 1024 or 4096: NT even)
    f32x4 acc[4][4] = {};

    // per-thread staging base addresses (global) and per-wave LDS bases
    const size_t aoff = (bm + (size_t)(w * 16 + srow)) * (size_t)K + scol;
    const size_t boff = (bn + (size_t)(w * 16 + srow)) * (size_t)K + scol;
    const size_t k128 = (size_t)128 * K;
    bf16_t* const Asw = As + w * 512;
    bf16_t* const Bsw = Bs + w * 512;

    // stage A-plane (256x32, 2 sweeps) + B-plane (128x32, 1 sweep) into slot s
    auto stageAB = [&](int s, size_t kcol) {
        gld16(A + aoff + kcol,        Asw + s * 8192);
        gld16(A + aoff + k128 + kcol, Asw + s * 8192 + 4096);
        gld16(Bt + boff + kcol,       Bsw + s * 4096);
    };

    // one phase: read slot rd, compute, stage slot st <- column stk
    auto phase = [&](int rd, int st, size_t stk) {
        bf16x8 af[4], bfv[4];
        const bf16_t* Ap = As + rd * 8192;
        const bf16_t* Bp = Bs + rd * 4096;
#pragma unroll
        for (int i = 0; i < 4; i++)
            af[i] = *(const bf16x8*)&Ap[(wm * 64 + i * 16 + fr) * 32 + swz];
#pragma unroll
        for (int j = 0; j < 4; j++)
            bfv[j] = *(const bf16x8*)&Bp[(wn * 64 + j * 16 + fr) * 32 + swz];
        stageAB(st, stk);
        __builtin_amdgcn_s_barrier();
        __builtin_amdgcn_s_setprio(1);
#pragma unroll
        for (int i = 0; i < 4; i++)
#pragma unroll
            for (int j = 0; j < 4; j++)
                acc[i][j] = __builtin_amdgcn_mfma_f32_16x16x32_bf16(af[i], bfv[j],
                                                                    acc[i][j], 0, 0, 0);
        __builtin_amdgcn_s_setprio(0);
        asm volatile("s_waitcnt vmcnt(6)" ::: "memory");
        __builtin_amdgcn_s_barrier();
    };

    // prologue: S0 <- t0.p0, S1 <- t0.p1, S2 <- t1.p0 (9 loads); wait S0 done
    stageAB(0, 0);
    stageAB(1, 32);
    stageAB(2, 64);
    asm volatile("s_waitcnt vmcnt(6)" ::: "memory");
    __builtin_amdgcn_s_barrier();

    for (int t = 0; t < NT; t += 2) {
        const size_t t1 = (t + 1 < NT) ? t + 1 : NT - 1;   // clamped tail keeps the
        const size_t t2 = (t + 2 < NT) ? t + 2 : NT - 1;   // vmcnt count uniform
        const size_t t3 = (t + 3 < NT) ? t + 3 : NT - 1;
        phase(0, 3, t1 * 64 + 32);   // read t.p0     ; stage S3 <- (t+1).p1
        phase(1, 0, t2 * 64);        // read t.p1     ; stage S0 <- (t+2).p0
        phase(2, 1, t2 * 64 + 32);   // read (t+1).p0 ; stage S1 <- (t+2).p1
        phase(3, 2, t3 * 64);        // read (t+1).p1 ; stage S2 <- (t+3).p0
    }
    // drain: no gld16 may be in flight when the block retires (LDS dealloc)
    asm volatile("s_waitcnt vmcnt(0)" ::: "memory");

    // epilogue: C layout col = lane&15, row = quad*4 + reg
#pragma unroll
    for (int j = 0; j < 4; j++) {
        const size_t c = bn + wn * 64 + j * 16 + fr;
        const float bv = bias[c];
#pragma unroll
        for (int i = 0; i < 4; i++) {
            const size_t rbase = bm + wm * 64 + i * 16 + quad * 4;
#pragma unroll
            for (int r = 0; r < 4; r++) {
                const size_t idx = (rbase + r) * (size_t)Ntot + c;
                float v = acc[i][j][r] + bv;
                if constexpr (EPI == 0) {
                    outb[idx] = (bf16_t)v;
                } else if constexpr (EPI == 1) {
                    outf[idx] = v + res[idx];
                } else {
                    float g = 0.5f * v * (1.0f + erff(v * 0.70710678118654752f));
                    outb[idx] = (bf16_t)g;
                }
            }
        }
    }
}

// ---------------------------------------------------------------------------
// Flash attention: one block per (b, h, 64 Q rows). K-tiles of 128.
// No max-rescaling (scores sigma ~3, overflow needs ~26 sigma). Ps aliases Ks.
// ---------------------------------------------------------------------------
__global__ __launch_bounds__(256) void flash_attn(const bf16_t* __restrict__ q,
                                                  const bf16_t* __restrict__ kmat,
                                                  const bf16_t* __restrict__ vT,
                                                  const float* __restrict__ wts,
                                                  bf16_t* __restrict__ ao, int ldq) {
    __shared__ bf16_t Ks[128 * 72];   // [key][dk] pad 64->72; aliased by Ps[64][136]
    __shared__ bf16_t Vs[64 * 136];   // [dk][key] pad 128->136
    bf16_t* Ps = Ks;

    const int tid = threadIdx.x;
    const int wave = tid >> 6, lane = tid & 63;
    const int fr = lane & 15, quad = lane >> 4;
    const int fk = quad * 8;
    const int bh = blockIdx.y, b = bh >> 4, h = bh & 15;
    const int q0 = blockIdx.x * 64;

    const size_t qrow = (size_t)(b * MM + q0 + wave * 16 + fr) * ldq + h * DKK;
    const bf16x8 aq0 = *(const bf16x8*)(q + qrow + fk);
    const bf16x8 aq1 = *(const bf16x8*)(q + qrow + 32 + fk);

    f32x4 oacc[4] = {};
    float lrow[4] = {0.f, 0.f, 0.f, 0.f};

    for (int kt = 0; kt < MM; kt += 128) {
        __syncthreads();
#pragma unroll
        for (int rr = 0; rr < 4; rr++) {
            const int key = rr * 32 + (tid >> 3);
            const int dkc = (tid & 7) * 8;
            *(bf16x8*)(&Ks[key * 72 + dkc]) =
                *(const bf16x8*)(kmat + (size_t)(b * MM + kt + key) * ldq + h * DKK + dkc);
            const int dkr = rr * 16 + (tid >> 4);
            const int kc = (tid & 15) * 8;
            *(bf16x8*)(&Vs[dkr * 136 + kc]) =
                *(const bf16x8*)(vT + (size_t)(bh * DKK + dkr) * MM + kt + kc);
        }
        __syncthreads();

        f32x4 s[8];
#pragma unroll
        for (int ni = 0; ni < 8; ni++) {
            const bf16_t* kp = &Ks[(ni * 16 + fr) * 72];
            f32x4 z = {0.f, 0.f, 0.f, 0.f};
            z = __builtin_amdgcn_mfma_f32_16x16x32_bf16(aq0, *(const bf16x8*)(kp + fk), z, 0, 0, 0);
            z = __builtin_amdgcn_mfma_f32_16x16x32_bf16(aq1, *(const bf16x8*)(kp + 32 + fk), z, 0, 0, 0);
            const float wv = wts[b * MM + kt + ni * 16 + fr];
#pragma unroll
            for (int r = 0; r < 4; r++) s[ni][r] = __expf(z[r] * 0.125f + wv);
        }

        float rs[4] = {0.f, 0.f, 0.f, 0.f};
#pragma unroll
        for (int ni = 0; ni < 8; ni++)
#pragma unroll
            for (int r = 0; r < 4; r++) rs[r] += s[ni][r];
#pragma unroll
        for (int off = 1; off < 16; off <<= 1)
#pragma unroll
            for (int r = 0; r < 4; r++) rs[r] += __shfl_xor(rs[r], off, 16);
#pragma unroll
        for (int r = 0; r < 4; r++) lrow[r] += rs[r];

        __syncthreads();   // all waves done reading Ks before P overwrites it

#pragma unroll
        for (int ni = 0; ni < 8; ni++)
#pragma unroll
            for (int r = 0; r < 4; r++)
                Ps[(wave * 16 + quad * 4 + r) * 136 + ni * 16 + fr] = (bf16_t)s[ni][r];

#pragma unroll
        for (int c2 = 0; c2 < 4; c2++) {
            const bf16x8 ap = *(const bf16x8*)(&Ps[(wave * 16 + fr) * 136 + c2 * 32 + fk]);
#pragma unroll
            for (int ni = 0; ni < 4; ni++) {
                const bf16x8 bv = *(const bf16x8*)(&Vs[(ni * 16 + fr) * 136 + c2 * 32 + fk]);
                oacc[ni] = __builtin_amdgcn_mfma_f32_16x16x32_bf16(ap, bv, oacc[ni], 0, 0, 0);
            }
        }
    }

    const size_t orow = (size_t)(b * MM + q0 + wave * 16 + quad * 4);
#pragma unroll
    for (int ni = 0; ni < 4; ni++)
#pragma unroll
        for (int r = 0; r < 4; r++) {
            const float ov = oacc[ni][r] / lrow[r];
            ao[(orow + r) * DD + h * DKK + ni * 16 + fr] = (bf16_t)ov;
        }
}

// ---------------------------------------------------------------------------
// LayerNorm over rows of D=1024: out fp32 + bf16 copy
// ---------------------------------------------------------------------------
__global__ __launch_bounds__(256) void ln_k(const float* __restrict__ in,
                                            const float* __restrict__ g,
                                            const float* __restrict__ be,
                                            float* __restrict__ xout,
                                            bf16_t* __restrict__ xb) {
    const int row = blockIdx.x, t = threadIdx.x;
    const float* rp = in + (size_t)row * DD;
    float4 v = *(const float4*)(rp + t * 4);
    float s = v.x + v.y + v.z + v.w;
    float ss = v.x * v.x + v.y * v.y + v.z * v.z + v.w * v.w;
    for (int off = 1; off < 64; off <<= 1) {
        s += __shfl_xor(s, off);
        ss += __shfl_xor(ss, off);
    }
    __shared__ float sb[4], ssb[4];
    if ((t & 63) == 0) { sb[t >> 6] = s; ssb[t >> 6] = ss; }
    __syncthreads();
    s = sb[0] + sb[1] + sb[2] + sb[3];
    ss = ssb[0] + ssb[1] + ssb[2] + ssb[3];
    const float mu = s * (1.0f / DD);
    const float var = ss * (1.0f / DD) - mu * mu;
    const float rstd = rsqrtf(var + 1e-5f);
    float4 gg = *(const float4*)(g + t * 4);
    float4 bb = *(const float4*)(be + t * 4);
    float o0 = (v.x - mu) * rstd * gg.x + bb.x;
    float o1 = (v.y - mu) * rstd * gg.y + bb.y;
    float o2 = (v.z - mu) * rstd * gg.z + bb.z;
    float o3 = (v.w - mu) * rstd * gg.w + bb.w;
    *(float4*)(xout + (size_t)row * DD + t * 4) = make_float4(o0, o1, o2, o3);
    bf16x4 ob;
    ob[0] = (bf16_t)o0; ob[1] = (bf16_t)o1; ob[2] = (bf16_t)o2; ob[3] = (bf16_t)o3;
    *(bf16x4*)(xb + (size_t)row * DD + t * 4) = ob;
}

// ---------------------------------------------------------------------------
extern "C" void kernel_launch(void* const* d_in, const int* in_sizes, int n_in,
                              void* d_out, int out_size, void* d_ws, size_t ws_size,
                              hipStream_t stream) {
    const float* embeds = (const float*)d_in[0];
    const float* wts    = (const float*)d_in[1];
    const float* Wq = (const float*)d_in[2];
    const float* bq = (const float*)d_in[3];
    const float* Wk = (const float*)d_in[4];
    const float* bk = (const float*)d_in[5];
    const float* Wv = (const float*)d_in[6];
    const float* bv = (const float*)d_in[7];
    const float* Wo = (const float*)d_in[8];
    const float* bo = (const float*)d_in[9];
    const float* W1 = (const float*)d_in[10];
    const float* b1 = (const float*)d_in[11];
    const float* W2 = (const float*)d_in[12];
    const float* b2 = (const float*)d_in[13];
    const float* g1 = (const float*)d_in[14];
    const float* be1 = (const float*)d_in[15];
    const float* g2 = (const float*)d_in[16];
    const float* be2 = (const float*)d_in[17];
    float* x = (float*)d_out;

    char* p = (char*)d_ws;
    auto take = [&](size_t n) { char* r = p; p += (n + 255) & ~(size_t)255; return r; };
    const size_t nBMD = (size_t)BB * MM * DD;
    bf16_t* xb   = (bf16_t*)take(nBMD * 2);
    bf16_t* qkvb = (bf16_t*)take(nBMD * 3 * 2);
    bf16_t* vTb  = (bf16_t*)take(nBMD * 2);
    float*  r1   = (float*)take(nBMD * 4);
    float*  x1   = (float*)take(nBMD * 4);
    bf16_t* hb   = (bf16_t*)take((size_t)BB * MM * FF * 2);
    bf16_t* qkvT = (bf16_t*)take((size_t)3 * DD * DD * 2);
    bf16_t* WoT  = (bf16_t*)take((size_t)DD * DD * 2);
    bf16_t* W1T  = (bf16_t*)take((size_t)DD * FF * 2);
    bf16_t* W2T  = (bf16_t*)take((size_t)DD * FF * 2);
    float*  qkvB = (float*)take((size_t)NL * 3072 * 4);
    bf16_t* aob  = hb;   // hb is free until FFN1
    bf16_t* x1b  = xb;   // xb is dead after the QKV GEMM

    cvt_x<<<8192, 256, 0, stream>>>(embeds, x, xb);
    concat_bias<<<dim3(3, NL), 256, 0, stream>>>(bq, bk, bv, qkvB);

    const dim3 gQKV(3072 / 128, (BB * MM) / 256);   // (24, 32) = 768 -> 3 rounds
    const dim3 gDD(DD / 128, (BB * MM) / 256);      // (8, 32)  = 256 -> 1 round
    const dim3 gF1(FF / 128, (BB * MM) / 256);      // (32, 32) = 1024 -> 4 rounds

    for (int l = 0; l < NL; l++) {
        transpose_all<<<12288, 256, 0, stream>>>(
            Wq + (size_t)l * DD * DD, Wk + (size_t)l * DD * DD,
            Wv + (size_t)l * DD * DD, Wo + (size_t)l * DD * DD,
            W1 + (size_t)l * DD * FF, W2 + (size_t)l * FF * DD,
            qkvT, WoT, W1T, W2T);

        gemm_k<0><<<gQKV, 512, 0, stream>>>(xb, qkvT, qkvB + (size_t)l * 3072,
                                            nullptr, qkvb, nullptr, DD, 3072);

        transpose_v_k<<<dim3(16, 128), 256, 0, stream>>>(qkvb + 2048, vTb, 3072);
        flash_attn<<<dim3(16, 128), 256, 0, stream>>>(qkvb, qkvb + 1024, vTb, wts, aob, 3072);

        gemm_k<1><<<gDD, 512, 0, stream>>>(aob, WoT, bo + (size_t)l * DD, x, nullptr, r1, DD, DD);
        ln_k<<<BB * MM, 256, 0, stream>>>(r1, g1 + (size_t)l * DD, be1 + (size_t)l * DD, x1, x1b);

        gemm_k<2><<<gF1, 512, 0, stream>>>(x1b, W1T, b1 + (size_t)l * FF, nullptr, hb, nullptr, DD, FF);
        gemm_k<1><<<gDD, 512, 0, stream>>>(hb, W2T, b2 + (size_t)l * DD, x1, nullptr, r1, FF, DD);
        ln_k<<<BB * MM, 256, 0, stream>>>(r1, g2 + (size_t)l * DD, be2 + (size_t)l * DD, x, xb);
    }
}